// Round 2
// baseline (596.028 us; speedup 1.0000x reference)
//
#include <hip/hip_runtime.h>

// ESN forward (collapsed): out[row, r] = (1 - lr) * tanh(dot(x[row, 0:8], w_in[r, 0:8]))
// row = b*T + t, rows = 256*4096 = 1048576, R = 128, I = 8.
// d (input 2) is dead: reference multiplies it by a zero state.
//
// Memory-bound: 512 MiB out + 32 MiB in -> ~86 us floor at 6.3 TB/s.
// NOTE: measured dur_us includes the harness's 2 GiB re-poison fill (~337 us
// at 6.3 TB/s, visible in rocprof as fillBufferAligned). Kernel-only time is
// dur_us - ~337.
//
// v3: plain (cached) stores instead of __builtin_nontemporal_store. The
// harness's own fills prove the normal store path sustains 6.3 TB/s; nt
// stores bypass L2 write-combining and ack at HBM, gating each iteration's
// store-register reuse on HBM ack latency. v2's x-prefetch pipeline kept.

constexpr int kI          = 8;
constexpr int kR          = 128;
constexpr int kRows       = 256 * 4096;              // 1048576
constexpr int kBlocks     = 2048;
constexpr int kRowsPerBlk = 8;                       // 256 threads / 32 lanes-per-row
constexpr int kRowStride  = kBlocks * kRowsPerBlk;   // 16384
constexpr int kIters      = kRows / kRowStride;      // 64 (exact)
static_assert(kRows % kRowStride == 0, "trip count must be exact");

typedef float v4f __attribute__((ext_vector_type(4)));

__device__ __forceinline__ v4f compute4(const float w[4][8], v4f x0, v4f x1,
                                        float scale) {
    v4f o;
#pragma unroll
    for (int j = 0; j < 4; ++j) {
        float acc = x0.x * w[j][0];
        acc = fmaf(x0.y, w[j][1], acc);
        acc = fmaf(x0.z, w[j][2], acc);
        acc = fmaf(x0.w, w[j][3], acc);
        acc = fmaf(x1.x, w[j][4], acc);
        acc = fmaf(x1.y, w[j][5], acc);
        acc = fmaf(x1.z, w[j][6], acc);
        acc = fmaf(x1.w, w[j][7], acc);
        // tanh(a) = 1 - 2/(exp(2a)+1); exp(2a)->inf gives rcp->0 -> 1 (no NaN).
        float e  = __expf(2.0f * acc);
        float th = 1.0f - 2.0f * __builtin_amdgcn_rcpf(e + 1.0f);
        o[j] = scale * th;
    }
    return o;
}

__global__ __launch_bounds__(256) void esn_kernel(
    const float* __restrict__ x,     // [kRows, 8]
    const float* __restrict__ w_in,  // [128, 8]
    const float* __restrict__ lr,    // [1]
    float* __restrict__ out)         // [kRows, 128]
{
    const float scale = 1.0f - lr[0];

    const int lane     = threadIdx.x & 31;  // 32 threads per row; lane covers r = lane*4 .. lane*4+3
    const int rowInBlk = threadIdx.x >> 5;  // 8 rows per block iteration

    // Load this lane's 4 w_in rows (32 consecutive floats) into registers once.
    float w[4][8];
    {
        const v4f* wp = (const v4f*)(w_in) + lane * 8; // lane*32 floats
#pragma unroll
        for (int j = 0; j < 4; ++j) {
            v4f a = wp[2 * j];
            v4f b = wp[2 * j + 1];
            w[j][0] = a.x; w[j][1] = a.y; w[j][2] = a.z; w[j][3] = a.w;
            w[j][4] = b.x; w[j][5] = b.y; w[j][6] = b.z; w[j][7] = b.w;
        }
    }

    const int row = (int)blockIdx.x * kRowsPerBlk + rowInBlk;
    const v4f* xp = (const v4f*)(x + row * kI);        // 2 v4f per row
    v4f* op = (v4f*)(out + (size_t)row * kR) + lane;   // this lane's 16B slot

    // Prologue: load row for iteration 0.
    v4f cx0 = xp[0];
    v4f cx1 = xp[1];

    // Steady state: issue NEXT row's loads, THEN compute+store current row.
    for (int it = 0; it < kIters - 1; ++it) {
        xp += kRowStride * (kI / 4);                   // +16384 rows
        v4f nx0 = xp[0];
        v4f nx1 = xp[1];

        v4f o = compute4(w, cx0, cx1, scale);
        *op = o;                                       // plain cached store
        op += kRowStride * (kR / 4);

        cx0 = nx0;
        cx1 = nx1;
    }

    // Epilogue: last row (no prefetch past end of x).
    v4f o = compute4(w, cx0, cx1, scale);
    *op = o;
}

extern "C" void kernel_launch(void* const* d_in, const int* in_sizes, int n_in,
                              void* d_out, int out_size, void* d_ws, size_t ws_size,
                              hipStream_t stream) {
    const float* x    = (const float*)d_in[0];
    const float* w_in = (const float*)d_in[1];
    // d_in[2] = d  -- unused (reference multiplies it by a zero state)
    const float* lr   = (const float*)d_in[3];
    float* out        = (float*)d_out;

    // 2048 blocks x 256 threads: 8 rows/block-iter, exactly 64 pipelined iters;
    // 8 blocks/CU residency on 256 CUs, 32 waves/CU (max occupancy).
    esn_kernel<<<dim3(kBlocks), dim3(256), 0, stream>>>(x, w_in, lr, out);
}

// Round 4
// 580.408 us; speedup vs baseline: 1.0269x; 1.0269x over previous
//
#include <hip/hip_runtime.h>

// ESN forward (collapsed): out[row, r] = (1 - lr) * tanh(dot(x[row, 0:8], w_in[r, 0:8]))
// row = b*T + t, rows = 256*4096 = 1048576, R = 128, I = 8.
// d (input 2) is dead: reference multiplies it by a zero state.
//
// Memory-bound: 512 MiB out + 32 MiB in -> ~86 us floor at 6.3 TB/s.
// NOTE: measured dur_us includes the harness's 2 GiB re-poison fill (~340 us,
// visible in rocprof as fillBufferAligned). Kernel-only time = dur_us - ~340.
//
// v4 (resubmitted after acquisition timeout — unmeasured): 4-row unroll +
// ping-pong group prefetch. Previous variants all kept exactly ONE store in
// flight per wave (the waitcnt for next-row x loads, being oldest-first,
// drained every older store) -> ~1 KB/wave in flight -> ~2.2 TB/s. This
// version keeps 4 stores + 8-16 loads outstanding per wave (~4.6 KB/wave,
// ~60 KB/CU), enough by Little's law to saturate the write path that the
// harness's own fills prove runs at 6.3 TB/s.

constexpr int kI          = 8;
constexpr int kR          = 128;
constexpr int kRows       = 256 * 4096;               // 1048576
constexpr int kBlocks     = 2048;
constexpr int kRowsPerBlk = 8;                        // 8 half-waves per block
constexpr int kU          = 4;                        // rows per thread per group
constexpr int kBlkRows    = kRowsPerBlk * kU;         // 32 rows per block per group
constexpr int kGroupRows  = kBlocks * kBlkRows;       // 65536
constexpr int kGroups     = kRows / kGroupRows;       // 16
static_assert(kRows % kGroupRows == 0, "exact trip count");
static_assert(kGroups % 2 == 0, "ping-pong needs even group count");

typedef float v4f __attribute__((ext_vector_type(4)));

struct XRow { v4f a, b; };

__device__ __forceinline__ void load_group(const float* __restrict__ x,
                                           int row0, XRow r[kU]) {
#pragma unroll
    for (int u = 0; u < kU; ++u) {
        const v4f* xp = (const v4f*)(x + (row0 + u * kRowsPerBlk) * kI);
        r[u].a = xp[0];
        r[u].b = xp[1];
    }
}

__device__ __forceinline__ v4f compute4(const float w[4][8], v4f x0, v4f x1,
                                        float scale, float m2s) {
    v4f o;
#pragma unroll
    for (int j = 0; j < 4; ++j) {
        float acc = x0.x * w[j][0];
        acc = fmaf(x0.y, w[j][1], acc);
        acc = fmaf(x0.z, w[j][2], acc);
        acc = fmaf(x0.w, w[j][3], acc);
        acc = fmaf(x1.x, w[j][4], acc);
        acc = fmaf(x1.y, w[j][5], acc);
        acc = fmaf(x1.z, w[j][6], acc);
        acc = fmaf(x1.w, w[j][7], acc);
        // scale*tanh(a) = scale - 2*scale/(exp(2a)+1); exp->inf gives rcp->0 (no NaN).
        float e = __expf(2.0f * acc);
        float r = __builtin_amdgcn_rcpf(e + 1.0f);
        o[j] = fmaf(m2s, r, scale);
    }
    return o;
}

__device__ __forceinline__ void cs_group(const float w[4][8], const XRow r[kU],
                                         float scale, float m2s,
                                         float* __restrict__ out,
                                         int row0, int lane) {
#pragma unroll
    for (int u = 0; u < kU; ++u) {
        v4f o = compute4(w, r[u].a, r[u].b, scale, m2s);
        v4f* op = (v4f*)(out + (size_t)(row0 + u * kRowsPerBlk) * kR) + lane;
        *op = o;
    }
}

__global__ __launch_bounds__(256) void esn_kernel(
    const float* __restrict__ x,     // [kRows, 8]
    const float* __restrict__ w_in,  // [128, 8]
    const float* __restrict__ lr,    // [1]
    float* __restrict__ out)         // [kRows, 128]
{
    const float scale = 1.0f - lr[0];
    const float m2s   = -2.0f * scale;

    const int lane     = threadIdx.x & 31;  // 32 lanes per row; lane covers r = lane*4 .. lane*4+3
    const int rowInBlk = threadIdx.x >> 5;

    // Load this lane's 4 w_in rows (32 consecutive floats) into registers once.
    float w[4][8];
    {
        const v4f* wp = (const v4f*)(w_in) + lane * 8;
#pragma unroll
        for (int j = 0; j < 4; ++j) {
            v4f a = wp[2 * j];
            v4f b = wp[2 * j + 1];
            w[j][0] = a.x; w[j][1] = a.y; w[j][2] = a.z; w[j][3] = a.w;
            w[j][4] = b.x; w[j][5] = b.y; w[j][6] = b.z; w[j][7] = b.w;
        }
    }

    // Base row for group g: g*kGroupRows + blockIdx*32 + rowInBlk (u adds 8).
    const int base = (int)blockIdx.x * kBlkRows + rowInBlk;

    XRow A[kU], B[kU];

    // Prologue: load group 0 into A.
    load_group(x, base, A);

    // Steady state (2 groups per body):
    //   issue loads(g+1)->B, compute+store(g) from A,
    //   issue loads(g+2)->A, compute+store(g+1) from B.
    // Every waitcnt-for-loads leaves the 4 just-issued stores + 8 newer loads
    // outstanding -> ~4.6 KB in flight per wave at all times.
    for (int g = 0; g < kGroups - 2; g += 2) {
        load_group(x, base + (g + 1) * kGroupRows, B);
        cs_group(w, A, scale, m2s, out, base + g * kGroupRows, lane);
        load_group(x, base + (g + 2) * kGroupRows, A);
        cs_group(w, B, scale, m2s, out, base + (g + 1) * kGroupRows, lane);
    }

    // Tail: groups kGroups-2 (in A) and kGroups-1.
    load_group(x, base + (kGroups - 1) * kGroupRows, B);
    cs_group(w, A, scale, m2s, out, base + (kGroups - 2) * kGroupRows, lane);
    cs_group(w, B, scale, m2s, out, base + (kGroups - 1) * kGroupRows, lane);
}

extern "C" void kernel_launch(void* const* d_in, const int* in_sizes, int n_in,
                              void* d_out, int out_size, void* d_ws, size_t ws_size,
                              hipStream_t stream) {
    const float* x    = (const float*)d_in[0];
    const float* w_in = (const float*)d_in[1];
    // d_in[2] = d  -- unused (reference multiplies it by a zero state)
    const float* lr   = (const float*)d_in[3];
    float* out        = (float*)d_out;

    // 2048 blocks x 256 threads: 32 rows/block/group, 16 groups, 8 blocks/CU.
    esn_kernel<<<dim3(kBlocks), dim3(256), 0, stream>>>(x, w_in, lr, out);
}